// Round 12
// baseline (278.695 us; speedup 1.0000x reference)
//
#include <hip/hip_runtime.h>

typedef unsigned short u16;
typedef __bf16 bf16x8 __attribute__((ext_vector_type(8)));
typedef float f32x4 __attribute__((ext_vector_type(4)));
typedef u16 u16x8 __attribute__((ext_vector_type(8), may_alias));
typedef u16 u16x4 __attribute__((ext_vector_type(4), may_alias));
typedef unsigned int u32x4 __attribute__((ext_vector_type(4)));

#define D_MODEL 1024
#define D_MLP   4096
#define D_HEAD  64
#define N_HEADS 16
#define SEQ     2048
#define BATCH   2
#define BS      (BATCH * SEQ)   // 4096 rows
#define QKV_N   3072
// Q pre-scale: (1/sqrt(64)) * log2(e) so attention works in exp2 domain
#define QSCALE  0.18033688011112042f
// key-split: 40 (qb,seg) units per bh (512-key segments), 1280 blocks total
#define NSEG_TOTAL 40

__device__ __forceinline__ u16 f2b(float f) {
  unsigned u = __builtin_bit_cast(unsigned, f);
  u += 0x7fffu + ((u >> 16) & 1u);           // round-to-nearest-even
  return (u16)(u >> 16);
}

__device__ __forceinline__ unsigned cvtpk_bf16(float lo, float hi) {
  unsigned r;
  asm("v_cvt_pk_bf16_f32 %0, %1, %2" : "=v"(r) : "v"(lo), "v"(hi));
  return r;
}

__device__ __forceinline__ void gload_lds16(const u16* g, u16* l) {
  __builtin_amdgcn_global_load_lds(
      (const __attribute__((address_space(1))) unsigned int*)g,
      (__attribute__((address_space(3))) unsigned int*)l, 16, 0, 0);
}

// ---------------- fp32 -> bf16 convert (4 elems/thread) ----------------
__global__ __launch_bounds__(256) void cvt_kernel(const float* __restrict__ in,
                                                  u16* __restrict__ out, int n4) {
  int i = blockIdx.x * 256 + threadIdx.x;
  if (i >= n4) return;
  float4 v = ((const float4*)in)[i];
  u16x4 o;
  o[0] = f2b(v.x); o[1] = f2b(v.y); o[2] = f2b(v.z); o[3] = f2b(v.w);
  ((u16x4*)out)[i] = o;
}

// ---------------- generic bf16 GEMM: C[M,N] = A[M,K] @ B[N,K]^T ----------------
// 128x128 tile, BK=64, 4 waves, 16x16x32 MFMA, global_load_lds(16B),
// XOR slot-swizzle applied to the GLOBAL source (LDS stays linear) + same XOR on reads.
// 1D grid + XCD/supertile remap: xcd = bid&7 owns a 16-row x (gx/4)-col rectangle
// of 128x128 tiles, iterated column-major (B-panel L2-hot for 16 blocks).
// MODE 0: QKV. col<1024: Q*QSCALE -> qk (LD 2048); col<2048: K -> qk; else V -> vt transposed
// MODE 1: o = acc + resid[idx]; outf = o; outb = bf16(o)     (attn out + residual)
// MODE 2: o = relu(acc + bias[col]); outb = bf16(o)          (mlp in)
// MODE 3: split-K=2 (virtual gx=16, z=bx>>3): partial f32 -> outf[z*M*N + idx]
template<int MODE>
__global__ __launch_bounds__(256) void gemm_bt(
    const u16* __restrict__ A, const u16* __restrict__ Bw,
    int M, int N, int K,
    u16* __restrict__ outb, float* __restrict__ outf,
    const float* __restrict__ resid, const float* __restrict__ bias,
    u16* __restrict__ vtp, int gx)
{
  __shared__ u16 Asm_[128 * 64];
  __shared__ u16 Bsm_[128 * 64];
  const int t = threadIdx.x;
  const int lane = t & 63;
  const int l15 = lane & 15, l4 = lane >> 4;
  const int w = t >> 6;
  const int wr = w >> 1, wc = w & 1;

  // XCD/supertile remap (gy = 32 rows always; RY=2, CX=4, rh=16)
  const int xcd = blockIdx.x & 7;
  const int local = blockIdx.x >> 3;
  const int rw = gx >> 2;
  const int rx = xcd & 3, ry = xcd >> 2;
  const int c = local >> 4, r0 = local & 15;
  int bx = rx * rw + c;
  const int by = ry * 16 + r0;
  int z = 0;
  if (MODE == 3) { z = bx >> 3; bx &= 7; }
  const int m0 = by * 128;
  const int n0 = bx * 128;
  const int kb = (MODE == 3) ? z * (K >> 1) : 0;
  const int ke = (MODE == 3) ? kb + (K >> 1) : K;

  f32x4 acc[4][4] = {};

  for (int k0 = kb; k0 < ke; k0 += 64) {
    __syncthreads();
#pragma unroll
    for (int i = 0; i < 4; ++i) {
      int s = i * 256 + t;                 // 16B slot index 0..1023
      int row = s >> 3;
      int sl = s & 7;
      int gc = ((sl ^ (row & 7)) << 3);    // pre-swizzled global k-chunk
      const u16* ga = A + (size_t)(m0 + row) * K + (k0 + gc);
      const u16* gb = Bw + (size_t)(n0 + row) * K + (k0 + gc);
      u16* la = Asm_ + (i * 256 + (t & ~63)) * 8;   // wave-uniform base
      u16* lb = Bsm_ + (i * 256 + (t & ~63)) * 8;
      gload_lds16(ga, la);
      gload_lds16(gb, lb);
    }
    asm volatile("s_waitcnt vmcnt(0)" ::: "memory");
    __syncthreads();
#pragma unroll
    for (int kk = 0; kk < 2; ++kk) {
      bf16x8 af[4], bfr[4];
#pragma unroll
      for (int mi = 0; mi < 4; ++mi) {
        int row = wr * 64 + mi * 16 + l15;
        int sl2 = (kk * 4 + l4) ^ (row & 7);
        u16x8 ua = *(const u16x8*)(Asm_ + row * 64 + sl2 * 8);
        af[mi] = __builtin_bit_cast(bf16x8, ua);
      }
#pragma unroll
      for (int ni = 0; ni < 4; ++ni) {
        int row = wc * 64 + ni * 16 + l15;
        int sl2 = (kk * 4 + l4) ^ (row & 7);
        u16x8 ub = *(const u16x8*)(Bsm_ + row * 64 + sl2 * 8);
        bfr[ni] = __builtin_bit_cast(bf16x8, ub);
      }
#pragma unroll
      for (int mi = 0; mi < 4; ++mi)
#pragma unroll
        for (int ni = 0; ni < 4; ++ni)
          acc[mi][ni] = __builtin_amdgcn_mfma_f32_16x16x32_bf16(af[mi], bfr[ni], acc[mi][ni], 0, 0, 0);
    }
  }

#pragma unroll
  for (int mi = 0; mi < 4; ++mi) {
    int rowb = m0 + wr * 64 + mi * 16 + l4 * 4;
#pragma unroll
    for (int ni = 0; ni < 4; ++ni) {
      int col = n0 + wc * 64 + ni * 16 + l15;
#pragma unroll
      for (int r = 0; r < 4; ++r) {
        float v = acc[mi][ni][r];
        int row = rowb + r;
        if (MODE == 0) {
          if (col < 2048) {
            float o = (col < 1024) ? v * QSCALE : v;
            outb[((size_t)row << 11) + col] = f2b(o);
          } else {
            int c2 = col - 2048;                      // c2 = h*64 + d
            size_t vi = (((size_t)((row >> 11) * 1024 + c2)) << 11) + (row & (SEQ - 1));
            vtp[vi] = f2b(v);
          }
        } else if (MODE == 3) {
          outf[(size_t)z * M * N + (size_t)row * N + col] = v;
        } else {
          size_t idx = (size_t)row * N + col;
          if (MODE == 1) {
            float o = v + resid[idx];
            outf[idx] = o;
            outb[idx] = f2b(o);
          } else {
            float o = v + bias[col];
            o = o > 0.f ? o : 0.f;
            outb[idx] = f2b(o);
          }
        }
      }
    }
  }
}

// ---------------- split-K reduce: out = p0 + p1 + resid + bias ----------------
__global__ __launch_bounds__(256) void reduce2_kernel(const float* __restrict__ part,
                                                      const float* __restrict__ resid,
                                                      const float* __restrict__ bias,
                                                      float* __restrict__ out) {
  const int i = blockIdx.x * 256 + threadIdx.x;    // float4 index over BS*1024/4
  float4 a = ((const float4*)part)[i];
  float4 b = ((const float4*)(part + (size_t)BS * D_MODEL))[i];
  float4 r = ((const float4*)resid)[i];
  float4 bi = ((const float4*)bias)[i & 255];      // D_MODEL/4 = 256
  float4 o;
  o.x = a.x + b.x + r.x + bi.x;
  o.y = a.y + b.y + r.y + bi.y;
  o.z = a.z + b.z + r.z + bi.z;
  o.w = a.w + b.w + r.w + bi.w;
  ((float4*)out)[i] = o;
}

// ---------------- causal flash attention, KVBLK=64, KEY-SPLIT partials ----------------
// 1280 blocks: bh = blk&31; u = 39 - (blk>>5) -> (qb, seg), NS(qb) = (qb>>2)+1
// (512-key segments = 8 x 64-key tiles). Block = 4 waves x 32 q-rows of one (b,h,qb).
// compute() is BYTE-IDENTICAL to the proven R11 kernel (builtin-only MFMA, full-K
// packed PV, pre-permuted V LDS, XOR-swizzled K). Each block emits UNNORMALIZED
// partials: zpart f32 [slot][128][64] (z[q][d]), ml float2 [slot][128] (m, l in exp2
// domain); slot = u*32 + bh. A merge kernel combines the <=4 segments per (bh,qb).
__global__ __launch_bounds__(256) void attn_kernel(const u16* __restrict__ qk,
                                                   const u16* __restrict__ vT,
                                                   float* __restrict__ zpart,
                                                   float* __restrict__ ml)
{
  __shared__ u16 Kl[2][64 * 64];
  __shared__ u16 Vl[2][64 * 72];
  const int t = threadIdx.x;
  const int w = t >> 6;
  const int lane = t & 63;
  const int l15 = lane & 15, l4 = lane >> 4;
  const int blk = blockIdx.x;
  const int bh = blk & 31;
  const int u = (NSEG_TOTAL - 1) - (blk >> 5);     // longest (high qb) first
  // invert u -> (qb, seg): u = C(qb) + seg, C(qb) = sum_{j<qb} ((j>>2)+1)
  int qb = 0, cc = 0;
  while (cc + ((qb >> 2) + 1) <= u) { cc += (qb >> 2) + 1; ++qb; }
  const int seg = u - cc;
  const int NSm1 = qb >> 2;                        // NS-1
  const int b = bh >> 4, h = bh & 15;
  const int q0w = qb * 128 + w * 32;
  const int myLastT = (4 * qb + w) >> 1;           // this wave's last 64-key tile
  const int ptbeg = seg * 8;
  const int ttendB = (seg == NSm1) ? (2 * qb + 1) : (ptbeg + 7);   // block loop bound

  // Q fragments: qf[sub][kc] for q rows q0w + sub*16 + l15
  bf16x8 qf[2][2];
#pragma unroll
  for (int s = 0; s < 2; ++s) {
    const u16* qp = qk + (((size_t)(b * SEQ + q0w + s * 16 + l15)) << 11) + h * 64 + l4 * 8;
    qf[s][0] = __builtin_bit_cast(bf16x8, *(const u16x8*)(qp));
    qf[s][1] = __builtin_bit_cast(bf16x8, *(const u16x8*)(qp + 32));
  }

  // K staging: thread t -> tile row srow (shot0) / srow+32 (shot1), slot t&7
  const int srow = t >> 3;                      // 0..31
  const int sgc = ((t & 7) ^ (srow & 7)) * 8;   // pre-swizzled k-chunk
  const u16* kgbase = qk + (((size_t)(b * SEQ + srow)) << 11) + 1024 + h * 64 + sgc;
  u16* kldst = &Kl[0][0] + (t & ~63) * 8;       // wave-uniform base (HW adds lane*16B)
  // V staging (permuted): thread t -> row vd2 (0..63), quad q4 (0..3)
  const int vd2 = t >> 2, q4 = t & 3;
  const u16* vgbase = vT + (((size_t)(bh * 64 + vd2)) << 11);

  f32x4 zacc[2][4] = {};
  float m_run[2] = {-1e30f, -1e30f}, l_run[2] = {0.f, 0.f};

  auto compute = [&](int buf, int tt) {
    // K fragments (swizzled read): kf[ks][kc], key row = ks*16 + l15
    bf16x8 kf[4][2];
#pragma unroll
    for (int ks = 0; ks < 4; ++ks) {
      int row = ks * 16 + l15;
#pragma unroll
      for (int kc = 0; kc < 2; ++kc) {
        int slot = (kc * 4 + l4) ^ (row & 7);
        kf[ks][kc] = __builtin_bit_cast(bf16x8, *(const u16x8*)&Kl[buf][row * 64 + slot * 8]);
      }
    }
    // V fragments (pre-permuted rows): vf[g][dn], one 16B read each
    bf16x8 vf[2][4];
#pragma unroll
    for (int g = 0; g < 2; ++g)
#pragma unroll
      for (int dn = 0; dn < 4; ++dn)
        vf[g][dn] = __builtin_bit_cast(bf16x8,
            *(const u16x8*)&Vl[buf][(dn * 16 + l15) * 72 + g * 32 + l4 * 8]);

    const bool last = (tt == myLastT);
#pragma unroll
    for (int s = 0; s < 2; ++s) {
      f32x4 sf[4] = {};
      __builtin_amdgcn_s_setprio(1);
#pragma unroll
      for (int ks = 0; ks < 4; ++ks) {
        sf[ks] = __builtin_amdgcn_mfma_f32_16x16x32_bf16(kf[ks][0], qf[s][0], sf[ks], 0, 0, 0);
        sf[ks] = __builtin_amdgcn_mfma_f32_16x16x32_bf16(kf[ks][1], qf[s][1], sf[ks], 0, 0, 0);
      }
      __builtin_amdgcn_s_setprio(0);

      if (last) {
        // absolute causal mask: key = tt*64 + ks*16 + l4*4 + r vs q = q0w + s*16 + l15
        const int qq = q0w + s * 16 + l15;
        const int pb = tt * 64 + l4 * 4;
#pragma unroll
        for (int ks = 0; ks < 4; ++ks)
#pragma unroll
          for (int r = 0; r < 4; ++r)
            sf[ks][r] = (pb + ks * 16 + r <= qq) ? sf[ks][r] : -1e30f;
      }

      // online softmax over 64 keys: one reduce chain (16 lane-local + 2 shfl)
      float mk[4];
#pragma unroll
      for (int ks = 0; ks < 4; ++ks)
        mk[ks] = fmaxf(fmaxf(sf[ks][0], sf[ks][1]), fmaxf(sf[ks][2], sf[ks][3]));
      float mt = fmaxf(fmaxf(mk[0], mk[1]), fmaxf(mk[2], mk[3]));
      mt = fmaxf(mt, __shfl_xor(mt, 16));
      mt = fmaxf(mt, __shfl_xor(mt, 32));
      const float mn = fmaxf(m_run[s], mt);
      const float sc = __builtin_amdgcn_exp2f(m_run[s] - mn);
      m_run[s] = mn;
      float pv[4][4];
      float rs = 0.f;
#pragma unroll
      for (int ks = 0; ks < 4; ++ks)
#pragma unroll
        for (int r = 0; r < 4; ++r) {
          pv[ks][r] = __builtin_amdgcn_exp2f(sf[ks][r] - mn);
          rs += pv[ks][r];
        }
      rs += __shfl_xor(rs, 16);
      rs += __shfl_xor(rs, 32);
      l_run[s] = l_run[s] * sc + rs;

      // shuffle-free rescale (sc uniform across the l4 groups of this q)
#pragma unroll
      for (int dn = 0; dn < 4; ++dn)
#pragma unroll
        for (int r = 0; r < 4; ++r) zacc[s][dn][r] *= sc;

      // pack P, full-K: pa[g] elems 0-3 = subtile 2g quad, 4-7 = subtile 2g+1 quad
      bf16x8 pa[2];
#pragma unroll
      for (int g = 0; g < 2; ++g) {
        u32x4 pu;
        pu[0] = cvtpk_bf16(pv[2 * g][0], pv[2 * g][1]);
        pu[1] = cvtpk_bf16(pv[2 * g][2], pv[2 * g][3]);
        pu[2] = cvtpk_bf16(pv[2 * g + 1][0], pv[2 * g + 1][1]);
        pu[3] = cvtpk_bf16(pv[2 * g + 1][2], pv[2 * g + 1][3]);
        pa[g] = __builtin_bit_cast(bf16x8, pu);
      }

      // transposed PV, full K=32 per MFMA: zacc[dn] = z^T[d = dn*16 + l4*4+r][q = l15]
      __builtin_amdgcn_s_setprio(1);
#pragma unroll
      for (int dn = 0; dn < 4; ++dn) {
        zacc[s][dn] = __builtin_amdgcn_mfma_f32_16x16x32_bf16(vf[0][dn], pa[0], zacc[s][dn], 0, 0, 0);
        zacc[s][dn] = __builtin_amdgcn_mfma_f32_16x16x32_bf16(vf[1][dn], pa[1], zacc[s][dn], 0, 0, 0);
      }
      __builtin_amdgcn_s_setprio(0);
    }
  };

  // prologue: stage tile ptbeg (K: 2 shots; V: 2 permuted 16B writes)
  gload_lds16(kgbase + ((size_t)ptbeg << 17), kldst);
  gload_lds16(kgbase + ((size_t)ptbeg << 17) + ((size_t)1 << 16), kldst + 2048);
  {
    const u16* vg = vgbase + ptbeg * 64;
    u16x4 a0 = *(const u16x4*)(vg + q4 * 4);
    u16x4 a1 = *(const u16x4*)(vg + 16 + q4 * 4);
    u16x4 b0 = *(const u16x4*)(vg + 32 + q4 * 4);
    u16x4 b1 = *(const u16x4*)(vg + 48 + q4 * 4);
    *(u16x8*)&Vl[0][vd2 * 72 + q4 * 8] =
        __builtin_shufflevector(a0, a1, 0, 1, 2, 3, 4, 5, 6, 7);
    *(u16x8*)&Vl[0][vd2 * 72 + 32 + q4 * 8] =
        __builtin_shufflevector(b0, b1, 0, 1, 2, 3, 4, 5, 6, 7);
  }
  asm volatile("s_waitcnt vmcnt(0)" ::: "memory");
  __syncthreads();

  int cur = 0;
  for (int tt = ptbeg; tt <= ttendB; ++tt) {
    const bool more = tt < ttendB;
    u16x4 a0, a1, b0, b1;
    if (more) {
      const u16* kg = kgbase + ((size_t)(tt + 1) << 17);
      u16* kld = kldst + (cur ^ 1) * 4096;
      gload_lds16(kg, kld);
      gload_lds16(kg + ((size_t)1 << 16), kld + 2048);
      const u16* vg = vgbase + (tt + 1) * 64;
      a0 = *(const u16x4*)(vg + q4 * 4);
      a1 = *(const u16x4*)(vg + 16 + q4 * 4);
      b0 = *(const u16x4*)(vg + 32 + q4 * 4);
      b1 = *(const u16x4*)(vg + 48 + q4 * 4);
    }
    if (tt <= myLastT) compute(cur, tt);
    if (more) {
      *(u16x8*)&Vl[cur ^ 1][vd2 * 72 + q4 * 8] =
          __builtin_shufflevector(a0, a1, 0, 1, 2, 3, 4, 5, 6, 7);
      *(u16x8*)&Vl[cur ^ 1][vd2 * 72 + 32 + q4 * 8] =
          __builtin_shufflevector(b0, b1, 0, 1, 2, 3, 4, 5, 6, 7);
    }
    asm volatile("s_waitcnt vmcnt(0)" ::: "memory");
    __syncthreads();
    cur ^= 1;
  }

  // epilogue: emit unnormalized partial (zpart z[q][d] f32, m, l); stats uniform per q
  const int slot = u * 32 + bh;
  float* zp = zpart + (size_t)slot * (128 * 64);
  float* mlp = ml + (size_t)slot * 256;
#pragma unroll
  for (int s = 0; s < 2; ++s) {
    const int qrow = 32 * w + s * 16 + l15;
#pragma unroll
    for (int dn = 0; dn < 4; ++dn)
      *(f32x4*)(zp + qrow * 64 + dn * 16 + l4 * 4) = zacc[s][dn];
    if (l4 == 0) {
      mlp[qrow * 2 + 0] = m_run[s];
      mlp[qrow * 2 + 1] = l_run[s];
    }
  }
}

// ---------------- merge key-split partials -> zb (bf16) ----------------
// 512 blocks: bh = blk&31, qb = blk>>5. Combines NS = (qb>>2)+1 segments.
__global__ __launch_bounds__(256) void attn_merge(const float* __restrict__ zpart,
                                                  const float* __restrict__ ml,
                                                  u16* __restrict__ zb)
{
  const int blk = blockIdx.x;
  const int bh = blk & 31, qb = blk >> 5;
  const int b = bh >> 4, h = bh & 15;
  const int a = qb >> 2, bq = qb & 3;
  const int C = 2 * a * (a + 1) + bq * (a + 1);
  const int NS = a + 1;
  const float* zp0 = zpart + ((size_t)(C * 32 + bh)) * (128 * 64);
  const float* ml0 = ml + ((size_t)(C * 32 + bh)) * 256;

  for (int k = 0; k < 8; ++k) {
    const int e4 = threadIdx.x + k * 256;      // float4 index 0..2047
    const int q = e4 >> 4;
    float mg = -1e30f;
    for (int s2 = 0; s2 < NS; ++s2)
      mg = fmaxf(mg, ml0[s2 * (32 * 256) + q * 2]);
    float den = 0.f;
    float4 num = {0.f, 0.f, 0.f, 0.f};
    for (int s2 = 0; s2 < NS; ++s2) {
      const float mm = ml0[s2 * (32 * 256) + q * 2];
      const float ll = ml0[s2 * (32 * 256) + q * 2 + 1];
      const float wgt = __builtin_amdgcn_exp2f(mm - mg);
      den += wgt * ll;
      float4 zv = ((const float4*)(zp0 + (size_t)s2 * (32 * 128 * 64)))[e4];
      num.x += wgt * zv.x; num.y += wgt * zv.y;
      num.z += wgt * zv.z; num.w += wgt * zv.w;
    }
    const float inv = 1.f / den;
    const int d4 = e4 & 15;
    u16x4 o;
    o[0] = f2b(num.x * inv); o[1] = f2b(num.y * inv);
    o[2] = f2b(num.z * inv); o[3] = f2b(num.w * inv);
    *(u16x4*)(zb + ((size_t)(b * SEQ + qb * 128 + q)) * D_MODEL + h * 64 + d4 * 4) = o;
  }
}

// ---------------- launch ----------------
extern "C" void kernel_launch(void* const* d_in, const int* in_sizes, int n_in,
                              void* d_out, int out_size, void* d_ws, size_t ws_size,
                              hipStream_t stream) {
  const float* x     = (const float*)d_in[0];
  const float* W_K   = (const float*)d_in[1];
  const float* W_Q   = (const float*)d_in[2];
  const float* W_V   = (const float*)d_in[3];
  const float* W_O   = (const float*)d_in[4];
  const float* W_in  = (const float*)d_in[5];
  const float* b_in  = (const float*)d_in[6];
  const float* W_out = (const float*)d_in[7];
  const float* b_out = (const float*)d_in[8];
  float* out = (float*)d_out;

  char* p = (char*)d_ws;
  u16* xb    = (u16*)p;            p += (size_t)BS * D_MODEL * 2;
  u16* wqkv  = (u16*)p;            p += (size_t)QKV_N * D_MODEL * 2;   // also: ml during attn
  u16* wo_b  = (u16*)p;            p += (size_t)D_MODEL * D_MODEL * 2;
  u16* win_b = (u16*)p;            p += (size_t)D_MLP * D_MODEL * 2;
  u16* wout_b= (u16*)p;            p += (size_t)D_MODEL * D_MLP * 2;
  float* x1f = (float*)p;          p += (size_t)BS * D_MODEL * 4;      // also: zpart (with hb)
  u16* hb    = (u16*)p;            p += (size_t)BS * D_MLP * 2;
  // tail region: dead after their consumers; reused as split-K partials
  u16* qk    = (u16*)p;            p += (size_t)BS * 2048 * 2;        // Q|K, LD 2048
  u16* vt    = (u16*)p;            p += (size_t)BATCH * 1024 * SEQ * 2; // V^T per (b,h,d)
  u16* zb    = (u16*)p;            p += (size_t)BS * D_MODEL * 2;
  u16* x1b   = (u16*)p;            p += (size_t)BS * D_MODEL * 2;
  float* part = (float*)qk;        // 2 x BS x 1024 f32 = 33.6 MB over qk/vt/zb (dead then)
  float* zpart = x1f;              // 1280*128*64*4 = 41.9 MB over x1f+hb (50.3 MB), dead until MODE1
  float* mlbuf = (float*)wqkv;     // 1280*128*2*4 = 1.3 MB, wqkv dead after gemm<0>

  auto cvt = [&](const float* src, u16* dst, int n) {
    int n4 = n / 4;
    cvt_kernel<<<(n4 + 255) / 256, 256, 0, stream>>>(src, dst, n4);
  };
  cvt(x, xb, BS * D_MODEL);
  cvt(W_Q, wqkv + 0,                  N_HEADS * D_HEAD * D_MODEL);
  cvt(W_K, wqkv + 1024 * 1024,        N_HEADS * D_HEAD * D_MODEL);
  cvt(W_V, wqkv + 2 * 1024 * 1024,    N_HEADS * D_HEAD * D_MODEL);
  cvt(W_O, wo_b,  D_MODEL * D_MODEL);
  cvt(W_in, win_b, D_MLP * D_MODEL);
  cvt(W_out, wout_b, D_MODEL * D_MLP);

  // QKV projection: [4096,1024] @ [3072,1024]^T -> qk (Q prescaled | K) + vt (V^T)
  gemm_bt<0><<<dim3(24 * 32), 256, 0, stream>>>(
      xb, wqkv, BS, QKV_N, D_MODEL, qk, nullptr, nullptr, nullptr, vt, 24);

  // attention partials: 32 bh x 40 (qb,seg) units, KVBLK=64
  attn_kernel<<<dim3(32 * NSEG_TOTAL), 256, 0, stream>>>(qk, vt, zpart, mlbuf);
  // merge partials -> zb
  attn_merge<<<dim3(512), 256, 0, stream>>>(zpart, mlbuf, zb);

  // attn out + residual: z @ W_O^T + x -> x1 (f32 + bf16)
  gemm_bt<1><<<dim3(8 * 32), 256, 0, stream>>>(
      zb, wo_b, BS, D_MODEL, D_MODEL, x1b, x1f, x, nullptr, nullptr, 8);

  // MLP in: relu(x1 @ W_in^T + b_in) -> h
  gemm_bt<2><<<dim3(32 * 32), 256, 0, stream>>>(
      x1b, win_b, BS, D_MLP, D_MODEL, hb, nullptr, nullptr, b_in, nullptr, 32);

  // MLP out, split-K=2: h @ W_out^T -> part[z]
  gemm_bt<3><<<dim3(16 * 32), 256, 0, stream>>>(
      hb, wout_b, BS, D_MODEL, D_MLP, nullptr, part, nullptr, nullptr, nullptr, 16);

  // out = part0 + part1 + x1 + b_out
  reduce2_kernel<<<dim3(BS * D_MODEL / 4 / 256), 256, 0, stream>>>(part, x1f, b_out, out);
}

// Round 13
// 255.362 us; speedup vs baseline: 1.0914x; 1.0914x over previous
//
#include <hip/hip_runtime.h>

typedef unsigned short u16;
typedef __bf16 bf16x8 __attribute__((ext_vector_type(8)));
typedef float f32x4 __attribute__((ext_vector_type(4)));
typedef u16 u16x8 __attribute__((ext_vector_type(8), may_alias));
typedef u16 u16x4 __attribute__((ext_vector_type(4), may_alias));
typedef unsigned int u32x4 __attribute__((ext_vector_type(4)));

#define D_MODEL 1024
#define D_MLP   4096
#define D_HEAD  64
#define N_HEADS 16
#define SEQ     2048
#define BATCH   2
#define BS      (BATCH * SEQ)   // 4096 rows
#define QKV_N   3072
// Q pre-scale: (1/sqrt(64)) * log2(e) so attention works in exp2 domain
#define QSCALE  0.18033688011112042f

__device__ __forceinline__ u16 f2b(float f) {
  unsigned u = __builtin_bit_cast(unsigned, f);
  u += 0x7fffu + ((u >> 16) & 1u);           // round-to-nearest-even
  return (u16)(u >> 16);
}

__device__ __forceinline__ unsigned cvtpk_bf16(float lo, float hi) {
  unsigned r;
  asm("v_cvt_pk_bf16_f32 %0, %1, %2" : "=v"(r) : "v"(lo), "v"(hi));
  return r;
}

__device__ __forceinline__ void gload_lds16(const u16* g, u16* l) {
  __builtin_amdgcn_global_load_lds(
      (const __attribute__((address_space(1))) unsigned int*)g,
      (__attribute__((address_space(3))) unsigned int*)l, 16, 0, 0);
}

// ---------------- fp32 -> bf16 convert (4 elems/thread) ----------------
__global__ __launch_bounds__(256) void cvt_kernel(const float* __restrict__ in,
                                                  u16* __restrict__ out, int n4) {
  int i = blockIdx.x * 256 + threadIdx.x;
  if (i >= n4) return;
  float4 v = ((const float4*)in)[i];
  u16x4 o;
  o[0] = f2b(v.x); o[1] = f2b(v.y); o[2] = f2b(v.z); o[3] = f2b(v.w);
  ((u16x4*)out)[i] = o;
}

// ---------------- generic bf16 GEMM: C[M,N] = A[M,K] @ B[N,K]^T ----------------
// 128x128 tile, BK=64, 4 waves, 16x16x32 MFMA, global_load_lds(16B),
// XOR slot-swizzle applied to the GLOBAL source (LDS stays linear) + same XOR on reads.
// 1D grid + XCD/supertile remap: xcd = bid&7 owns a 16-row x (gx/4)-col rectangle
// of 128x128 tiles, iterated column-major (B-panel L2-hot for 16 blocks).
// MODE 0: QKV. col<1024: Q*QSCALE -> qk (LD 2048); col<2048: K -> qk; else V -> vt transposed
// MODE 1: o = acc + resid[idx]; outf = o; outb = bf16(o)     (attn out + residual)
// MODE 2: o = relu(acc + bias[col]); outb = bf16(o)          (mlp in)
// MODE 3: split-K=2 (virtual gx=16, z=bx>>3): partial f32 -> outf[z*M*N + idx]
template<int MODE>
__global__ __launch_bounds__(256) void gemm_bt(
    const u16* __restrict__ A, const u16* __restrict__ Bw,
    int M, int N, int K,
    u16* __restrict__ outb, float* __restrict__ outf,
    const float* __restrict__ resid, const float* __restrict__ bias,
    u16* __restrict__ vtp, int gx)
{
  __shared__ u16 Asm_[128 * 64];
  __shared__ u16 Bsm_[128 * 64];
  const int t = threadIdx.x;
  const int lane = t & 63;
  const int l15 = lane & 15, l4 = lane >> 4;
  const int w = t >> 6;
  const int wr = w >> 1, wc = w & 1;

  // XCD/supertile remap (gy = 32 rows always; RY=2, CX=4, rh=16)
  const int xcd = blockIdx.x & 7;
  const int local = blockIdx.x >> 3;
  const int rw = gx >> 2;
  const int rx = xcd & 3, ry = xcd >> 2;
  const int c = local >> 4, r0 = local & 15;
  int bx = rx * rw + c;
  const int by = ry * 16 + r0;
  int z = 0;
  if (MODE == 3) { z = bx >> 3; bx &= 7; }
  const int m0 = by * 128;
  const int n0 = bx * 128;
  const int kb = (MODE == 3) ? z * (K >> 1) : 0;
  const int ke = (MODE == 3) ? kb + (K >> 1) : K;

  f32x4 acc[4][4] = {};

  for (int k0 = kb; k0 < ke; k0 += 64) {
    __syncthreads();
#pragma unroll
    for (int i = 0; i < 4; ++i) {
      int s = i * 256 + t;                 // 16B slot index 0..1023
      int row = s >> 3;
      int sl = s & 7;
      int gc = ((sl ^ (row & 7)) << 3);    // pre-swizzled global k-chunk
      const u16* ga = A + (size_t)(m0 + row) * K + (k0 + gc);
      const u16* gb = Bw + (size_t)(n0 + row) * K + (k0 + gc);
      u16* la = Asm_ + (i * 256 + (t & ~63)) * 8;   // wave-uniform base
      u16* lb = Bsm_ + (i * 256 + (t & ~63)) * 8;
      gload_lds16(ga, la);
      gload_lds16(gb, lb);
    }
    asm volatile("s_waitcnt vmcnt(0)" ::: "memory");
    __syncthreads();
#pragma unroll
    for (int kk = 0; kk < 2; ++kk) {
      bf16x8 af[4], bfr[4];
#pragma unroll
      for (int mi = 0; mi < 4; ++mi) {
        int row = wr * 64 + mi * 16 + l15;
        int sl2 = (kk * 4 + l4) ^ (row & 7);
        u16x8 ua = *(const u16x8*)(Asm_ + row * 64 + sl2 * 8);
        af[mi] = __builtin_bit_cast(bf16x8, ua);
      }
#pragma unroll
      for (int ni = 0; ni < 4; ++ni) {
        int row = wc * 64 + ni * 16 + l15;
        int sl2 = (kk * 4 + l4) ^ (row & 7);
        u16x8 ub = *(const u16x8*)(Bsm_ + row * 64 + sl2 * 8);
        bfr[ni] = __builtin_bit_cast(bf16x8, ub);
      }
#pragma unroll
      for (int mi = 0; mi < 4; ++mi)
#pragma unroll
        for (int ni = 0; ni < 4; ++ni)
          acc[mi][ni] = __builtin_amdgcn_mfma_f32_16x16x32_bf16(af[mi], bfr[ni], acc[mi][ni], 0, 0, 0);
    }
  }

#pragma unroll
  for (int mi = 0; mi < 4; ++mi) {
    int rowb = m0 + wr * 64 + mi * 16 + l4 * 4;
#pragma unroll
    for (int ni = 0; ni < 4; ++ni) {
      int col = n0 + wc * 64 + ni * 16 + l15;
#pragma unroll
      for (int r = 0; r < 4; ++r) {
        float v = acc[mi][ni][r];
        int row = rowb + r;
        if (MODE == 0) {
          if (col < 2048) {
            float o = (col < 1024) ? v * QSCALE : v;
            outb[((size_t)row << 11) + col] = f2b(o);
          } else {
            int c2 = col - 2048;                      // c2 = h*64 + d
            size_t vi = (((size_t)((row >> 11) * 1024 + c2)) << 11) + (row & (SEQ - 1));
            vtp[vi] = f2b(v);
          }
        } else if (MODE == 3) {
          outf[(size_t)z * M * N + (size_t)row * N + col] = v;
        } else {
          size_t idx = (size_t)row * N + col;
          if (MODE == 1) {
            float o = v + resid[idx];
            outf[idx] = o;
            outb[idx] = f2b(o);
          } else {
            float o = v + bias[col];
            o = o > 0.f ? o : 0.f;
            outb[idx] = f2b(o);
          }
        }
      }
    }
  }
}

// ---------------- split-K reduce: out = p0 + p1 + resid + bias ----------------
__global__ __launch_bounds__(256) void reduce2_kernel(const float* __restrict__ part,
                                                      const float* __restrict__ resid,
                                                      const float* __restrict__ bias,
                                                      float* __restrict__ out) {
  const int i = blockIdx.x * 256 + threadIdx.x;    // float4 index over BS*1024/4
  float4 a = ((const float4*)part)[i];
  float4 b = ((const float4*)(part + (size_t)BS * D_MODEL))[i];
  float4 r = ((const float4*)resid)[i];
  float4 bi = ((const float4*)bias)[i & 255];      // D_MODEL/4 = 256
  float4 o;
  o.x = a.x + b.x + r.x + bi.x;
  o.y = a.y + b.y + r.y + bi.y;
  o.z = a.z + b.z + r.z + bi.z;
  o.w = a.w + b.w + r.w + bi.w;
  ((float4*)out)[i] = o;
}

// ---------------- causal flash attention, block-shared LDS K/V, KVBLK=128 ----------------
// Block = 4 waves x 32 q-rows = 128 q-rows of one (b,h) share each staged K/V tile.
// Key tiles of 128, double-buffered LDS:
//   K  [128][64] u16, XOR slot-swizzled, 4 gload_lds shots/tile ((srow+32i)&7 == srow&7).
//   V^T[64][136] u16, reg-staged PRE-PERMUTED (4 g-slots/thread) so each PV A-frag is
//      one 16B read: Vl[d][g*32 + l4*8 + j] = vT[d][p0 + g*32 + l4*4 + (j&3) + 16*(j>>2)].
// With 128-key tiles EVERY wave's diagonal tile is tt == qb: uniform loop 0..qb, no
// per-wave gating; longest block = 16 iterations (was 32). One softmax reduce chain
// per 128 keys. PV full-K packed (pa[g] = quads of subtiles 2g, 2g+1). All MFMAs are
// the proven builtin. K-frags loaded inside the MFMA loop to cap VGPR pressure.
__global__ __launch_bounds__(256) void attn_kernel(const u16* __restrict__ qk,
                                                   const u16* __restrict__ vT,
                                                   u16* __restrict__ zb)
{
  __shared__ u16 Kl[2][128 * 64];
  __shared__ u16 Vl[2][64 * 136];
  const int t = threadIdx.x;
  const int w = t >> 6;
  const int lane = t & 63;
  const int l15 = lane & 15, l4 = lane >> 4;
  const int blk = blockIdx.x;
  const int bh = blk & 31;
  const int qb = 15 - (blk >> 5);         // longest blocks first
  const int b = bh >> 4, h = bh & 15;
  const int q0w = qb * 128 + w * 32;
  const int ttmax = qb;                   // diagonal tile for ALL waves

  // Q fragments: qf[sub][kc] for q rows q0w + sub*16 + l15
  bf16x8 qf[2][2];
#pragma unroll
  for (int s = 0; s < 2; ++s) {
    const u16* qp = qk + (((size_t)(b * SEQ + q0w + s * 16 + l15)) << 11) + h * 64 + l4 * 8;
    qf[s][0] = __builtin_bit_cast(bf16x8, *(const u16x8*)(qp));
    qf[s][1] = __builtin_bit_cast(bf16x8, *(const u16x8*)(qp + 32));
  }

  // K staging: thread t -> tile rows srow + 32*i (4 shots), slot t&7
  const int srow = t >> 3;                      // 0..31
  const int sgc = ((t & 7) ^ (srow & 7)) * 8;   // pre-swizzled k-chunk
  const u16* kgbase = qk + (((size_t)(b * SEQ + srow)) << 11) + 1024 + h * 64 + sgc;
  u16* kldst = &Kl[0][0] + (t & ~63) * 8;       // wave-uniform base (HW adds lane*16B)
  // V staging (permuted): thread t -> row vd2 (0..63), quad q4 (0..3), 4 g-slots
  const int vd2 = t >> 2, q4 = t & 3;
  const u16* vgbase = vT + (((size_t)(bh * 64 + vd2)) << 11);

  f32x4 zacc[2][4] = {};
  float m_run[2] = {-1e30f, -1e30f}, l_run[2] = {0.f, 0.f};

  auto stageK = [&](int buf, int tt) {
    const u16* kg = kgbase + ((size_t)tt << 18);    // 128 rows x 2048 u16
    u16* kld = kldst + buf * (128 * 64);
#pragma unroll
    for (int i = 0; i < 4; ++i)
      gload_lds16(kg + ((size_t)i << 16), kld + i * 2048);
  };

  auto compute = [&](int buf, int tt) {
    const bool last = (tt == ttmax);
#pragma unroll
    for (int s = 0; s < 2; ++s) {
      f32x4 sf[8] = {};
      __builtin_amdgcn_s_setprio(1);
#pragma unroll
      for (int ks = 0; ks < 8; ++ks) {
        const int row = ks * 16 + l15;
#pragma unroll
        for (int kc = 0; kc < 2; ++kc) {
          const int slot = (kc * 4 + l4) ^ (row & 7);
          bf16x8 kf = __builtin_bit_cast(bf16x8,
              *(const u16x8*)&Kl[buf][row * 64 + slot * 8]);
          sf[ks] = __builtin_amdgcn_mfma_f32_16x16x32_bf16(kf, qf[s][kc], sf[ks], 0, 0, 0);
        }
      }
      __builtin_amdgcn_s_setprio(0);

      if (last) {
        // absolute causal mask: key = tt*128 + ks*16 + l4*4 + r vs q = q0w + s*16 + l15
        const int qq = q0w + s * 16 + l15;
        const int pb = tt * 128 + l4 * 4;
#pragma unroll
        for (int ks = 0; ks < 8; ++ks)
#pragma unroll
          for (int r = 0; r < 4; ++r)
            sf[ks][r] = (pb + ks * 16 + r <= qq) ? sf[ks][r] : -1e30f;
      }

      // online softmax over 128 keys: ONE reduce chain (32 lane-local + 2 shfl)
      float mk[8];
#pragma unroll
      for (int ks = 0; ks < 8; ++ks)
        mk[ks] = fmaxf(fmaxf(sf[ks][0], sf[ks][1]), fmaxf(sf[ks][2], sf[ks][3]));
      float mt = fmaxf(fmaxf(fmaxf(mk[0], mk[1]), fmaxf(mk[2], mk[3])),
                       fmaxf(fmaxf(mk[4], mk[5]), fmaxf(mk[6], mk[7])));
      mt = fmaxf(mt, __shfl_xor(mt, 16));
      mt = fmaxf(mt, __shfl_xor(mt, 32));
      const float mn = fmaxf(m_run[s], mt);
      const float sc = __builtin_amdgcn_exp2f(m_run[s] - mn);
      m_run[s] = mn;
      float pv[8][4];
      float rs = 0.f;
#pragma unroll
      for (int ks = 0; ks < 8; ++ks)
#pragma unroll
        for (int r = 0; r < 4; ++r) {
          pv[ks][r] = __builtin_amdgcn_exp2f(sf[ks][r] - mn);
          rs += pv[ks][r];
        }
      rs += __shfl_xor(rs, 16);
      rs += __shfl_xor(rs, 32);
      l_run[s] = l_run[s] * sc + rs;

      // shuffle-free rescale (sc uniform across the l4 groups of this q)
#pragma unroll
      for (int dn = 0; dn < 4; ++dn)
#pragma unroll
        for (int r = 0; r < 4; ++r) zacc[s][dn][r] *= sc;

      // pack P full-K (pa[g] = quads of subtiles 2g, 2g+1) and PV
      __builtin_amdgcn_s_setprio(1);
#pragma unroll
      for (int g = 0; g < 4; ++g) {
        u32x4 pu;
        pu[0] = cvtpk_bf16(pv[2 * g][0], pv[2 * g][1]);
        pu[1] = cvtpk_bf16(pv[2 * g][2], pv[2 * g][3]);
        pu[2] = cvtpk_bf16(pv[2 * g + 1][0], pv[2 * g + 1][1]);
        pu[3] = cvtpk_bf16(pv[2 * g + 1][2], pv[2 * g + 1][3]);
        const bf16x8 pa = __builtin_bit_cast(bf16x8, pu);
#pragma unroll
        for (int dn = 0; dn < 4; ++dn) {
          bf16x8 vfr = __builtin_bit_cast(bf16x8,
              *(const u16x8*)&Vl[buf][(dn * 16 + l15) * 136 + g * 32 + l4 * 8]);
          zacc[s][dn] = __builtin_amdgcn_mfma_f32_16x16x32_bf16(vfr, pa, zacc[s][dn], 0, 0, 0);
        }
      }
      __builtin_amdgcn_s_setprio(0);
    }
  };

  // prologue: stage tile 0 (K: 4 shots; V: 4 permuted 16B writes)
  stageK(0, 0);
  {
#pragma unroll
    for (int g = 0; g < 4; ++g) {
      const u16* vg = vgbase + g * 32 + q4 * 4;
      u16x4 lo = *(const u16x4*)(vg);
      u16x4 hi = *(const u16x4*)(vg + 16);
      *(u16x8*)&Vl[0][vd2 * 136 + g * 32 + q4 * 8] =
          __builtin_shufflevector(lo, hi, 0, 1, 2, 3, 4, 5, 6, 7);
    }
  }
  asm volatile("s_waitcnt vmcnt(0)" ::: "memory");
  __syncthreads();

  int cur = 0;
  for (int tt = 0; tt <= ttmax; ++tt) {
    const bool more = tt < ttmax;
    u16x4 lo[4], hi[4];
    if (more) {
      stageK(cur ^ 1, tt + 1);
#pragma unroll
      for (int g = 0; g < 4; ++g) {
        const u16* vg = vgbase + (tt + 1) * 128 + g * 32 + q4 * 4;
        lo[g] = *(const u16x4*)(vg);
        hi[g] = *(const u16x4*)(vg + 16);
      }
    }
    compute(cur, tt);
    if (more) {
#pragma unroll
      for (int g = 0; g < 4; ++g)
        *(u16x8*)&Vl[cur ^ 1][vd2 * 136 + g * 32 + q4 * 8] =
            __builtin_shufflevector(lo[g], hi[g], 0, 1, 2, 3, 4, 5, 6, 7);
    }
    asm volatile("s_waitcnt vmcnt(0)" ::: "memory");
    __syncthreads();
    cur ^= 1;
  }

  // epilogue: z[q][h*64 + d], stats uniform per q
#pragma unroll
  for (int s = 0; s < 2; ++s) {
    const float inv = 1.f / l_run[s];
    const size_t rowoff = ((size_t)(b * SEQ + q0w + s * 16 + l15)) * D_MODEL + h * 64 + l4 * 4;
#pragma unroll
    for (int dn = 0; dn < 4; ++dn) {
      u16x4 o;
#pragma unroll
      for (int r = 0; r < 4; ++r) o[r] = f2b(zacc[s][dn][r] * inv);
      *(u16x4*)(zb + rowoff + dn * 16) = o;
    }
  }
}

// ---------------- launch ----------------
extern "C" void kernel_launch(void* const* d_in, const int* in_sizes, int n_in,
                              void* d_out, int out_size, void* d_ws, size_t ws_size,
                              hipStream_t stream) {
  const float* x     = (const float*)d_in[0];
  const float* W_K   = (const float*)d_in[1];
  const float* W_Q   = (const float*)d_in[2];
  const float* W_V   = (const float*)d_in[3];
  const float* W_O   = (const float*)d_in[4];
  const float* W_in  = (const float*)d_in[5];
  const float* b_in  = (const float*)d_in[6];
  const float* W_out = (const float*)d_in[7];
  const float* b_out = (const float*)d_in[8];
  float* out = (float*)d_out;

  char* p = (char*)d_ws;
  u16* xb    = (u16*)p;            p += (size_t)BS * D_MODEL * 2;
  u16* wqkv  = (u16*)p;            p += (size_t)QKV_N * D_MODEL * 2;
  u16* wo_b  = (u16*)p;            p += (size_t)D_MODEL * D_MODEL * 2;
  u16* win_b = (u16*)p;            p += (size_t)D_MLP * D_MODEL * 2;
  u16* wout_b= (u16*)p;            p += (size_t)D_MODEL * D_MLP * 2;
  float* x1f = (float*)p;          p += (size_t)BS * D_MODEL * 4;
  u16* hb    = (u16*)p;            p += (size_t)BS * D_MLP * 2;
  // tail region: dead after their consumers; reused as split-K partials
  u16* qk    = (u16*)p;            p += (size_t)BS * 2048 * 2;        // Q|K, LD 2048
  u16* vt    = (u16*)p;            p += (size_t)BATCH * 1024 * SEQ * 2; // V^T per (b,h,d)
  u16* zb    = (u16*)p;            p += (size_t)BS * D_MODEL * 2;
  u16* x1b   = (u16*)p;            p += (size_t)BS * D_MODEL * 2;
  float* part = (float*)qk;        // 2 x BS x 1024 f32 = 33.6 MB over qk/vt/zb/x1b (40 MB)

  auto cvt = [&](const float* src, u16* dst, int n) {
    int n4 = n / 4;
    cvt_kernel<<<(n4 + 255) / 256, 256, 0, stream>>>(src, dst, n4);
  };
  cvt(x, xb, BS * D_MODEL);
  cvt(W_Q, wqkv + 0,                  N_HEADS * D_HEAD * D_MODEL);
  cvt(W_K, wqkv + 1024 * 1024,        N_HEADS * D_HEAD * D_MODEL);
  cvt(W_V, wqkv + 2 * 1024 * 1024,    N_HEADS * D_HEAD * D_MODEL);
  cvt(W_O, wo_b,  D_MODEL * D_MODEL);
  cvt(W_in, win_b, D_MLP * D_MODEL);
  cvt(W_out, wout_b, D_MODEL * D_MLP);

  // QKV projection: [4096,1024] @ [3072,1024]^T -> qk (Q prescaled | K) + vt (V^T)
  gemm_bt<0><<<dim3(24 * 32), 256, 0, stream>>>(
      xb, wqkv, BS, QKV_N, D_MODEL, qk, nullptr, nullptr, nullptr, vt, 24);

  // attention: 32 bh x 16 q-blocks (128 rows each), KVBLK=128
  attn_kernel<<<dim3(512), 256, 0, stream>>>(qk, vt, zb);

  // attn out + residual: z @ W_O^T + x -> x1 (f32 + bf16)
  gemm_bt<1><<<dim3(8 * 32), 256, 0, stream>>>(
      zb, wo_b, BS, D_MODEL, D_MODEL, x1b, x1f, x, nullptr, nullptr, 8);

  // MLP in: relu(x1 @ W_in^T + b_in) -> h
  gemm_bt<2><<<dim3(32 * 32), 256, 0, stream>>>(
      x1b, win_b, BS, D_MLP, D_MODEL, hb, nullptr, nullptr, b_in, nullptr, 32);

  // MLP out, split-K=2: h @ W_out^T -> part[z]
  gemm_bt<3><<<dim3(16 * 32), 256, 0, stream>>>(
      hb, wout_b, BS, D_MODEL, D_MLP, nullptr, part, nullptr, nullptr, nullptr, 16);

  // out = part0 + part1 + x1 + b_out
  reduce2_kernel<<<dim3(BS * D_MODEL / 4 / 256), 256, 0, stream>>>(part, x1f, b_out, out);
}

// Round 14
// 254.486 us; speedup vs baseline: 1.0951x; 1.0034x over previous
//
#include <hip/hip_runtime.h>

typedef unsigned short u16;
typedef __bf16 bf16x8 __attribute__((ext_vector_type(8)));
typedef float f32x4 __attribute__((ext_vector_type(4)));
typedef u16 u16x8 __attribute__((ext_vector_type(8), may_alias));
typedef u16 u16x4 __attribute__((ext_vector_type(4), may_alias));
typedef unsigned int u32x4 __attribute__((ext_vector_type(4)));

#define D_MODEL 1024
#define D_MLP   4096
#define D_HEAD  64
#define N_HEADS 16
#define SEQ     2048
#define BATCH   2
#define BS      (BATCH * SEQ)   // 4096 rows
#define QKV_N   3072
// Q pre-scale: (1/sqrt(64)) * log2(e) so attention works in exp2 domain
#define QSCALE  0.18033688011112042f
// defer-max threshold (exp2 domain): P bounded by 2^8 = 256, bf16-safe
#define RESCALE_THR 8.0f

__device__ __forceinline__ u16 f2b(float f) {
  unsigned u = __builtin_bit_cast(unsigned, f);
  u += 0x7fffu + ((u >> 16) & 1u);           // round-to-nearest-even
  return (u16)(u >> 16);
}

__device__ __forceinline__ unsigned cvtpk_bf16(float lo, float hi) {
  unsigned r;
  asm("v_cvt_pk_bf16_f32 %0, %1, %2" : "=v"(r) : "v"(lo), "v"(hi));
  return r;
}

__device__ __forceinline__ void gload_lds16(const u16* g, u16* l) {
  __builtin_amdgcn_global_load_lds(
      (const __attribute__((address_space(1))) unsigned int*)g,
      (__attribute__((address_space(3))) unsigned int*)l, 16, 0, 0);
}

// ---------------- fp32 -> bf16 convert (4 elems/thread) ----------------
__global__ __launch_bounds__(256) void cvt_kernel(const float* __restrict__ in,
                                                  u16* __restrict__ out, int n4) {
  int i = blockIdx.x * 256 + threadIdx.x;
  if (i >= n4) return;
  float4 v = ((const float4*)in)[i];
  u16x4 o;
  o[0] = f2b(v.x); o[1] = f2b(v.y); o[2] = f2b(v.z); o[3] = f2b(v.w);
  ((u16x4*)out)[i] = o;
}

// ---------------- generic bf16 GEMM: C[M,N] = A[M,K] @ B[N,K]^T ----------------
// 128x128 tile, BK=64, 4 waves, 16x16x32 MFMA, global_load_lds(16B),
// XOR slot-swizzle applied to the GLOBAL source (LDS stays linear) + same XOR on reads.
// 1D grid + XCD/supertile remap: xcd = bid&7 owns a 16-row x (gx/4)-col rectangle
// of 128x128 tiles, iterated column-major (B-panel L2-hot for 16 blocks).
// MODE 0: QKV. col<1024: Q*QSCALE -> qk (LD 2048); col<2048: K -> qk; else V -> vt transposed
// MODE 1: o = acc + resid[idx]; outf = o; outb = bf16(o)     (attn out + residual)
// MODE 2: o = relu(acc + bias[col]); outb = bf16(o)          (mlp in)
// MODE 3: split-K=2 (virtual gx=16, z=bx>>3): partial f32 -> outf[z*M*N + idx]
template<int MODE>
__global__ __launch_bounds__(256) void gemm_bt(
    const u16* __restrict__ A, const u16* __restrict__ Bw,
    int M, int N, int K,
    u16* __restrict__ outb, float* __restrict__ outf,
    const float* __restrict__ resid, const float* __restrict__ bias,
    u16* __restrict__ vtp, int gx)
{
  __shared__ u16 Asm_[128 * 64];
  __shared__ u16 Bsm_[128 * 64];
  const int t = threadIdx.x;
  const int lane = t & 63;
  const int l15 = lane & 15, l4 = lane >> 4;
  const int w = t >> 6;
  const int wr = w >> 1, wc = w & 1;

  // XCD/supertile remap (gy = 32 rows always; RY=2, CX=4, rh=16)
  const int xcd = blockIdx.x & 7;
  const int local = blockIdx.x >> 3;
  const int rw = gx >> 2;
  const int rx = xcd & 3, ry = xcd >> 2;
  const int c = local >> 4, r0 = local & 15;
  int bx = rx * rw + c;
  const int by = ry * 16 + r0;
  int z = 0;
  if (MODE == 3) { z = bx >> 3; bx &= 7; }
  const int m0 = by * 128;
  const int n0 = bx * 128;
  const int kb = (MODE == 3) ? z * (K >> 1) : 0;
  const int ke = (MODE == 3) ? kb + (K >> 1) : K;

  f32x4 acc[4][4] = {};

  for (int k0 = kb; k0 < ke; k0 += 64) {
    __syncthreads();
#pragma unroll
    for (int i = 0; i < 4; ++i) {
      int s = i * 256 + t;                 // 16B slot index 0..1023
      int row = s >> 3;
      int sl = s & 7;
      int gc = ((sl ^ (row & 7)) << 3);    // pre-swizzled global k-chunk
      const u16* ga = A + (size_t)(m0 + row) * K + (k0 + gc);
      const u16* gb = Bw + (size_t)(n0 + row) * K + (k0 + gc);
      u16* la = Asm_ + (i * 256 + (t & ~63)) * 8;   // wave-uniform base
      u16* lb = Bsm_ + (i * 256 + (t & ~63)) * 8;
      gload_lds16(ga, la);
      gload_lds16(gb, lb);
    }
    asm volatile("s_waitcnt vmcnt(0)" ::: "memory");
    __syncthreads();
#pragma unroll
    for (int kk = 0; kk < 2; ++kk) {
      bf16x8 af[4], bfr[4];
#pragma unroll
      for (int mi = 0; mi < 4; ++mi) {
        int row = wr * 64 + mi * 16 + l15;
        int sl2 = (kk * 4 + l4) ^ (row & 7);
        u16x8 ua = *(const u16x8*)(Asm_ + row * 64 + sl2 * 8);
        af[mi] = __builtin_bit_cast(bf16x8, ua);
      }
#pragma unroll
      for (int ni = 0; ni < 4; ++ni) {
        int row = wc * 64 + ni * 16 + l15;
        int sl2 = (kk * 4 + l4) ^ (row & 7);
        u16x8 ub = *(const u16x8*)(Bsm_ + row * 64 + sl2 * 8);
        bfr[ni] = __builtin_bit_cast(bf16x8, ub);
      }
#pragma unroll
      for (int mi = 0; mi < 4; ++mi)
#pragma unroll
        for (int ni = 0; ni < 4; ++ni)
          acc[mi][ni] = __builtin_amdgcn_mfma_f32_16x16x32_bf16(af[mi], bfr[ni], acc[mi][ni], 0, 0, 0);
    }
  }

#pragma unroll
  for (int mi = 0; mi < 4; ++mi) {
    int rowb = m0 + wr * 64 + mi * 16 + l4 * 4;
#pragma unroll
    for (int ni = 0; ni < 4; ++ni) {
      int col = n0 + wc * 64 + ni * 16 + l15;
#pragma unroll
      for (int r = 0; r < 4; ++r) {
        float v = acc[mi][ni][r];
        int row = rowb + r;
        if (MODE == 0) {
          if (col < 2048) {
            float o = (col < 1024) ? v * QSCALE : v;
            outb[((size_t)row << 11) + col] = f2b(o);
          } else {
            int c2 = col - 2048;                      // c2 = h*64 + d
            size_t vi = (((size_t)((row >> 11) * 1024 + c2)) << 11) + (row & (SEQ - 1));
            vtp[vi] = f2b(v);
          }
        } else if (MODE == 3) {
          outf[(size_t)z * M * N + (size_t)row * N + col] = v;
        } else {
          size_t idx = (size_t)row * N + col;
          if (MODE == 1) {
            float o = v + resid[idx];
            outf[idx] = o;
            outb[idx] = f2b(o);
          } else {
            float o = v + bias[col];
            o = o > 0.f ? o : 0.f;
            outb[idx] = f2b(o);
          }
        }
      }
    }
  }
}

// ---------------- split-K reduce: out = p0 + p1 + resid + bias ----------------
__global__ __launch_bounds__(256) void reduce2_kernel(const float* __restrict__ part,
                                                      const float* __restrict__ resid,
                                                      const float* __restrict__ bias,
                                                      float* __restrict__ out) {
  const int i = blockIdx.x * 256 + threadIdx.x;    // float4 index over BS*1024/4
  float4 a = ((const float4*)part)[i];
  float4 b = ((const float4*)(part + (size_t)BS * D_MODEL))[i];
  float4 r = ((const float4*)resid)[i];
  float4 bi = ((const float4*)bias)[i & 255];      // D_MODEL/4 = 256
  float4 o;
  o.x = a.x + b.x + r.x + bi.x;
  o.y = a.y + b.y + r.y + bi.y;
  o.z = a.z + b.z + r.z + bi.z;
  o.w = a.w + b.w + r.w + bi.w;
  ((float4*)out)[i] = o;
}

// ---------------- causal flash attention, block-shared LDS K/V, KVBLK=128 ----------------
// Block = 4 waves x 32 q-rows = 128 q-rows of one (b,h) share each staged K/V tile.
// Key tiles of 128, double-buffered LDS:
//   K  [128][64] u16, XOR slot-swizzled, 4 gload_lds shots/tile ((srow+32i)&7 == srow&7).
//   V^T[64][136] u16, reg-staged PRE-PERMUTED (4 g-slots/thread) so each PV A-frag is
//      one 16B read.
// Uniform loop 0..qb (diagonal tile == qb for all waves). All MFMAs are the proven
// builtin. DEFER-MAX (T13): fast path (common) has ZERO shuffles and ZERO rescale
// (stale m, P <= 2^8, bf16-safe); slow path (first tile + rare growth, wave-uniform
// via __any) does the full 2-shfl max reduce + rescale. l_run is LANE-PARTIAL
// (sc uniform per q -> partials telescope exactly); reduced once at the epilogue.
__global__ __launch_bounds__(256) void attn_kernel(const u16* __restrict__ qk,
                                                   const u16* __restrict__ vT,
                                                   u16* __restrict__ zb)
{
  __shared__ u16 Kl[2][128 * 64];
  __shared__ u16 Vl[2][64 * 136];
  const int t = threadIdx.x;
  const int w = t >> 6;
  const int lane = t & 63;
  const int l15 = lane & 15, l4 = lane >> 4;
  const int blk = blockIdx.x;
  const int bh = blk & 31;
  const int qb = 15 - (blk >> 5);         // longest blocks first
  const int b = bh >> 4, h = bh & 15;
  const int q0w = qb * 128 + w * 32;
  const int ttmax = qb;                   // diagonal tile for ALL waves

  // Q fragments: qf[sub][kc] for q rows q0w + sub*16 + l15
  bf16x8 qf[2][2];
#pragma unroll
  for (int s = 0; s < 2; ++s) {
    const u16* qp = qk + (((size_t)(b * SEQ + q0w + s * 16 + l15)) << 11) + h * 64 + l4 * 8;
    qf[s][0] = __builtin_bit_cast(bf16x8, *(const u16x8*)(qp));
    qf[s][1] = __builtin_bit_cast(bf16x8, *(const u16x8*)(qp + 32));
  }

  // K staging: thread t -> tile rows srow + 32*i (4 shots), slot t&7
  const int srow = t >> 3;                      // 0..31
  const int sgc = ((t & 7) ^ (srow & 7)) * 8;   // pre-swizzled k-chunk
  const u16* kgbase = qk + (((size_t)(b * SEQ + srow)) << 11) + 1024 + h * 64 + sgc;
  u16* kldst = &Kl[0][0] + (t & ~63) * 8;       // wave-uniform base (HW adds lane*16B)
  // V staging (permuted): thread t -> row vd2 (0..63), quad q4 (0..3), 4 g-slots
  const int vd2 = t >> 2, q4 = t & 3;
  const u16* vgbase = vT + (((size_t)(bh * 64 + vd2)) << 11);

  f32x4 zacc[2][4] = {};
  float m_run[2] = {-1e30f, -1e30f};
  float l_run[2] = {0.f, 0.f};             // LANE-PARTIAL sums

  auto stageK = [&](int buf, int tt) {
    const u16* kg = kgbase + ((size_t)tt << 18);    // 128 rows x 2048 u16
    u16* kld = kldst + buf * (128 * 64);
#pragma unroll
    for (int i = 0; i < 4; ++i)
      gload_lds16(kg + ((size_t)i << 16), kld + i * 2048);
  };

  auto compute = [&](int buf, int tt) {
    const bool last = (tt == ttmax);
#pragma unroll
    for (int s = 0; s < 2; ++s) {
      f32x4 sf[8] = {};
      __builtin_amdgcn_s_setprio(1);
#pragma unroll
      for (int ks = 0; ks < 8; ++ks) {
        const int row = ks * 16 + l15;
#pragma unroll
        for (int kc = 0; kc < 2; ++kc) {
          const int slot = (kc * 4 + l4) ^ (row & 7);
          bf16x8 kf = __builtin_bit_cast(bf16x8,
              *(const u16x8*)&Kl[buf][row * 64 + slot * 8]);
          sf[ks] = __builtin_amdgcn_mfma_f32_16x16x32_bf16(kf, qf[s][kc], sf[ks], 0, 0, 0);
        }
      }
      __builtin_amdgcn_s_setprio(0);

      if (last) {
        // absolute causal mask: key = tt*128 + ks*16 + l4*4 + r vs q = q0w + s*16 + l15
        const int qq = q0w + s * 16 + l15;
        const int pb = tt * 128 + l4 * 4;
#pragma unroll
        for (int ks = 0; ks < 8; ++ks)
#pragma unroll
          for (int r = 0; r < 4; ++r)
            sf[ks][r] = (pb + ks * 16 + r <= qq) ? sf[ks][r] : -1e30f;
      }

      // lane-local max over this lane's 32 p-values
      float mk[8];
#pragma unroll
      for (int ks = 0; ks < 8; ++ks)
        mk[ks] = fmaxf(fmaxf(sf[ks][0], sf[ks][1]), fmaxf(sf[ks][2], sf[ks][3]));
      float mloc = fmaxf(fmaxf(fmaxf(mk[0], mk[1]), fmaxf(mk[2], mk[3])),
                         fmaxf(fmaxf(mk[4], mk[5]), fmaxf(mk[6], mk[7])));
      if (__any(mloc > m_run[s] + RESCALE_THR)) {
        // slow path: full max reduce + rescale (first tile and rare growth)
        float mt = mloc;
        mt = fmaxf(mt, __shfl_xor(mt, 16));
        mt = fmaxf(mt, __shfl_xor(mt, 32));
        const float mn = fmaxf(m_run[s], mt);
        const float sc = __builtin_amdgcn_exp2f(m_run[s] - mn);
        m_run[s] = mn;
        l_run[s] *= sc;
#pragma unroll
        for (int dn = 0; dn < 4; ++dn)
#pragma unroll
          for (int r = 0; r < 4; ++r) zacc[s][dn][r] *= sc;
      }

      // fast-path common part: P = exp2(score - m_run), lane-partial l update
      float pv[8][4];
      float rs = 0.f;
#pragma unroll
      for (int ks = 0; ks < 8; ++ks)
#pragma unroll
        for (int r = 0; r < 4; ++r) {
          pv[ks][r] = __builtin_amdgcn_exp2f(sf[ks][r] - m_run[s]);
          rs += pv[ks][r];
        }
      l_run[s] += rs;

      // pack P full-K (pa[g] = quads of subtiles 2g, 2g+1) and PV
      __builtin_amdgcn_s_setprio(1);
#pragma unroll
      for (int g = 0; g < 4; ++g) {
        u32x4 pu;
        pu[0] = cvtpk_bf16(pv[2 * g][0], pv[2 * g][1]);
        pu[1] = cvtpk_bf16(pv[2 * g][2], pv[2 * g][3]);
        pu[2] = cvtpk_bf16(pv[2 * g + 1][0], pv[2 * g + 1][1]);
        pu[3] = cvtpk_bf16(pv[2 * g + 1][2], pv[2 * g + 1][3]);
        const bf16x8 pa = __builtin_bit_cast(bf16x8, pu);
#pragma unroll
        for (int dn = 0; dn < 4; ++dn) {
          bf16x8 vfr = __builtin_bit_cast(bf16x8,
              *(const u16x8*)&Vl[buf][(dn * 16 + l15) * 136 + g * 32 + l4 * 8]);
          zacc[s][dn] = __builtin_amdgcn_mfma_f32_16x16x32_bf16(vfr, pa, zacc[s][dn], 0, 0, 0);
        }
      }
      __builtin_amdgcn_s_setprio(0);
    }
  };

  // prologue: stage tile 0 (K: 4 shots; V: 4 permuted 16B writes)
  stageK(0, 0);
  {
#pragma unroll
    for (int g = 0; g < 4; ++g) {
      const u16* vg = vgbase + g * 32 + q4 * 4;
      u16x4 lo = *(const u16x4*)(vg);
      u16x4 hi = *(const u16x4*)(vg + 16);
      *(u16x8*)&Vl[0][vd2 * 136 + g * 32 + q4 * 8] =
          __builtin_shufflevector(lo, hi, 0, 1, 2, 3, 4, 5, 6, 7);
    }
  }
  asm volatile("s_waitcnt vmcnt(0)" ::: "memory");
  __syncthreads();

  int cur = 0;
  for (int tt = 0; tt <= ttmax; ++tt) {
    const bool more = tt < ttmax;
    u16x4 lo[4], hi[4];
    if (more) {
      stageK(cur ^ 1, tt + 1);
#pragma unroll
      for (int g = 0; g < 4; ++g) {
        const u16* vg = vgbase + (tt + 1) * 128 + g * 32 + q4 * 4;
        lo[g] = *(const u16x4*)(vg);
        hi[g] = *(const u16x4*)(vg + 16);
      }
    }
    compute(cur, tt);
    if (more) {
#pragma unroll
      for (int g = 0; g < 4; ++g)
        *(u16x8*)&Vl[cur ^ 1][vd2 * 136 + g * 32 + q4 * 8] =
            __builtin_shufflevector(lo[g], hi[g], 0, 1, 2, 3, 4, 5, 6, 7);
    }
    asm volatile("s_waitcnt vmcnt(0)" ::: "memory");
    __syncthreads();
    cur ^= 1;
  }

  // epilogue: reduce lane-partial l (once), then z[q][h*64 + d]
#pragma unroll
  for (int s = 0; s < 2; ++s) {
    float lt = l_run[s];
    lt += __shfl_xor(lt, 16);
    lt += __shfl_xor(lt, 32);
    const float inv = 1.f / lt;
    const size_t rowoff = ((size_t)(b * SEQ + q0w + s * 16 + l15)) * D_MODEL + h * 64 + l4 * 4;
#pragma unroll
    for (int dn = 0; dn < 4; ++dn) {
      u16x4 o;
#pragma unroll
      for (int r = 0; r < 4; ++r) o[r] = f2b(zacc[s][dn][r] * inv);
      *(u16x4*)(zb + rowoff + dn * 16) = o;
    }
  }
}

// ---------------- launch ----------------
extern "C" void kernel_launch(void* const* d_in, const int* in_sizes, int n_in,
                              void* d_out, int out_size, void* d_ws, size_t ws_size,
                              hipStream_t stream) {
  const float* x     = (const float*)d_in[0];
  const float* W_K   = (const float*)d_in[1];
  const float* W_Q   = (const float*)d_in[2];
  const float* W_V   = (const float*)d_in[3];
  const float* W_O   = (const float*)d_in[4];
  const float* W_in  = (const float*)d_in[5];
  const float* b_in  = (const float*)d_in[6];
  const float* W_out = (const float*)d_in[7];
  const float* b_out = (const float*)d_in[8];
  float* out = (float*)d_out;

  char* p = (char*)d_ws;
  u16* xb    = (u16*)p;            p += (size_t)BS * D_MODEL * 2;
  u16* wqkv  = (u16*)p;            p += (size_t)QKV_N * D_MODEL * 2;
  u16* wo_b  = (u16*)p;            p += (size_t)D_MODEL * D_MODEL * 2;
  u16* win_b = (u16*)p;            p += (size_t)D_MLP * D_MODEL * 2;
  u16* wout_b= (u16*)p;            p += (size_t)D_MODEL * D_MLP * 2;
  float* x1f = (float*)p;          p += (size_t)BS * D_MODEL * 4;
  u16* hb    = (u16*)p;            p += (size_t)BS * D_MLP * 2;
  // tail region: dead after their consumers; reused as split-K partials
  u16* qk    = (u16*)p;            p += (size_t)BS * 2048 * 2;        // Q|K, LD 2048
  u16* vt    = (u16*)p;            p += (size_t)BATCH * 1024 * SEQ * 2; // V^T per (b,h,d)
  u16* zb    = (u16*)p;            p += (size_t)BS * D_MODEL * 2;
  u16* x1b   = (u16*)p;            p += (size_t)BS * D_MODEL * 2;
  float* part = (float*)qk;        // 2 x BS x 1024 f32 = 33.6 MB over qk/vt/zb/x1b (40 MB)

  auto cvt = [&](const float* src, u16* dst, int n) {
    int n4 = n / 4;
    cvt_kernel<<<(n4 + 255) / 256, 256, 0, stream>>>(src, dst, n4);
  };
  cvt(x, xb, BS * D_MODEL);
  cvt(W_Q, wqkv + 0,                  N_HEADS * D_HEAD * D_MODEL);
  cvt(W_K, wqkv + 1024 * 1024,        N_HEADS * D_HEAD * D_MODEL);
  cvt(W_V, wqkv + 2 * 1024 * 1024,    N_HEADS * D_HEAD * D_MODEL);
  cvt(W_O, wo_b,  D_MODEL * D_MODEL);
  cvt(W_in, win_b, D_MLP * D_MODEL);
  cvt(W_out, wout_b, D_MODEL * D_MLP);

  // QKV projection: [4096,1024] @ [3072,1024]^T -> qk (Q prescaled | K) + vt (V^T)
  gemm_bt<0><<<dim3(24 * 32), 256, 0, stream>>>(
      xb, wqkv, BS, QKV_N, D_MODEL, qk, nullptr, nullptr, nullptr, vt, 24);

  // attention: 32 bh x 16 q-blocks (128 rows each), KVBLK=128
  attn_kernel<<<dim3(512), 256, 0, stream>>>(qk, vt, zb);

  // attn out + residual: z @ W_O^T + x -> x1 (f32 + bf16)
  gemm_bt<1><<<dim3(8 * 32), 256, 0, stream>>>(
      zb, wo_b, BS, D_MODEL, D_MODEL, x1b, x1f, x, nullptr, nullptr, 8);

  // MLP in: relu(x1 @ W_in^T + b_in) -> h
  gemm_bt<2><<<dim3(32 * 32), 256, 0, stream>>>(
      x1b, win_b, BS, D_MLP, D_MODEL, hb, nullptr, nullptr, b_in, nullptr, 32);

  // MLP out, split-K=2: h @ W_out^T -> part[z]
  gemm_bt<3><<<dim3(16 * 32), 256, 0, stream>>>(
      hb, wout_b, BS, D_MODEL, D_MLP, nullptr, part, nullptr, nullptr, nullptr, 16);

  // out = part0 + part1 + x1 + b_out
  reduce2_kernel<<<dim3(BS * D_MODEL / 4 / 256), 256, 0, stream>>>(part, x1f, b_out, out);
}